// Round 10
// baseline (84.523 us; speedup 1.0000x reference)
//
#include <hip/hip_runtime.h>
#include <hip/hip_bf16.h>

#define S_LEN  2048
#define DHEAD  64
#define NHEADS 32
#define NBATCH 4
#define LOG2E  1.44269504f
// fp32(-2^32 * log2e): the one "masked" score in log2 domain. |real scores| << ulp here,
// so score+mask collapses to exactly CMASK, preserving the reference's fp32 semantics
// (all-visible-masked rows become uniform; fixup kernel finishes those).
#define CMASK  (-4294967296.0f * 1.44269504f)

typedef __attribute__((ext_vector_type(4)))  float f4;
typedef __attribute__((ext_vector_type(8)))  short bh8;    // 8 bf16
typedef __attribute__((ext_vector_type(16))) float f16x;   // 32x32 MFMA C/D
typedef __attribute__((ext_vector_type(4)))  int   i4;
typedef __attribute__((ext_vector_type(2)))  int   i2;
typedef unsigned short ushort_t;

static __device__ __forceinline__ unsigned short f2b(float f){
    unsigned int x = __builtin_bit_cast(unsigned int, f);
    x += 0x7FFFu + ((x >> 16) & 1u);
    return (unsigned short)(x >> 16);
}
static __device__ __forceinline__ float b2f(ushort_t u){
    return __builtin_bit_cast(float, ((unsigned)u) << 16);
}
static __device__ __forceinline__ int pack2(float a, float b){
    return (int)((unsigned)f2b(a) | ((unsigned)f2b(b) << 16));
}

// ---- prep: [0,2048) K->bf16 ; [2048,3072) V->bf16 transposed + col partials ;
//      [3072] mask bitwords ----
__global__ __launch_bounds__(256)
void prep(const float* __restrict__ K, const float* __restrict__ V,
          const int* __restrict__ M,
          ushort_t* __restrict__ Kb, ushort_t* __restrict__ Vt,
          float* __restrict__ colpart, unsigned* __restrict__ mbits)
{
    const int bid = blockIdx.x;
    const int tid = threadIdx.x;
    if (bid < 2048){                       // K conversion: 8 floats/thread
        const int i = bid * 256 + tid;
        const f4* p = (const f4*)(K + (size_t)i * 8);
        f4 a = p[0], b = p[1];
        bh8 w;
        #pragma unroll
        for (int k = 0; k < 4; ++k){ w[k] = (short)f2b(a[k]); w[k+4] = (short)f2b(b[k]); }
        *(bh8*)(Kb + (size_t)i * 8) = w;
    } else if (bid < 3072){                // V transpose -> Vt[h][d][s] bf16 (+ column sums)
        __shared__ short T[64][72];
        __shared__ float red[64][4];
        const int r2 = bid - 2048;         // 0..1023 = head*32 + slice
        const int head = r2 >> 5;
        const int kv0  = (r2 & 31) * 64;
        {
            const int r = tid >> 2;
            const int s = (tid & 3) * 16;
            const float* vp = V + ((size_t)head * S_LEN + kv0 + r) * DHEAD + s;
            f4 v0 = *(const f4*)(vp);
            f4 v1 = *(const f4*)(vp + 4);
            f4 v2 = *(const f4*)(vp + 8);
            f4 v3 = *(const f4*)(vp + 12);
            float vv[16];
            *(f4*)&vv[0] = v0; *(f4*)&vv[4] = v1; *(f4*)&vv[8] = v2; *(f4*)&vv[12] = v3;
            #pragma unroll
            for (int i = 0; i < 16; ++i) T[r][s + i] = (short)f2b(vv[i]);
        }
        __syncthreads();
        {
            const int d  = tid >> 2;
            const int k0 = (tid & 3) * 16;
            bh8 w0, w1;
            float s16 = 0.f;
            #pragma unroll
            for (int i = 0; i < 8; ++i){
                w0[i] = T[k0 + i][d];
                w1[i] = T[k0 + 8 + i][d];
                s16 += b2f((ushort_t)w0[i]) + b2f((ushort_t)w1[i]);
            }
            ushort_t* op = Vt + ((size_t)head * DHEAD + d) * S_LEN + kv0 + k0;
            *(bh8*)op       = w0;
            *(bh8*)(op + 8) = w1;
            red[d][tid & 3] = s16;
        }
        __syncthreads();
        if (tid < 64)
            colpart[(size_t)r2 * 64 + tid] =
                red[tid][0] + red[tid][1] + red[tid][2] + red[tid][3];
    } else {                               // mask bitwords: [batch][word], bit j = key masked
        const int* mp = M + ((size_t)(tid >> 6) << 11) + ((tid & 63) << 5);
        unsigned bits = 0u;
        #pragma unroll
        for (int j = 0; j < 32; j += 4){
            i4 v = *(const i4*)(mp + j);
            bits |= (v[0] != 0 ? (1u << j) : 0u) | (v[1] != 0 ? (2u << j) : 0u)
                  | (v[2] != 0 ? (4u << j) : 0u) | (v[3] != 0 ? (8u << j) : 0u);
        }
        mbits[tid] = bits;
    }
}

// ---- main attention: barrier-free. 4 waves/block, each wave owns 32 q-rows and
//      privately stages its KV tiles (32 keys) via global_load_lds + counted vmcnt ----
__global__ __launch_bounds__(256, 2)
void attn_main(const float* __restrict__ Q, const ushort_t* __restrict__ Kb,
               const ushort_t* __restrict__ Vt, const unsigned* __restrict__ mbits,
               float* __restrict__ Out)
{
    // per wave 16KB: [K0 4K][K1 4K][V0 4K][V1 4K]; P (2KB) aliases low half of V[cur]
    __shared__ char SMEM[4 * 16384];

    const int tid  = threadIdx.x;
    const int wave = tid >> 6;
    const int lane = tid & 63;
    const int lq   = lane & 31;   // q column owned by this lane
    const int hi   = lane >> 5;

    const int bid  = blockIdx.x;
    // heads clustered per XCD; j-pairing: bids c and c+256 give constant per-CU tile sum
    const int head = ((bid & 7) << 2) | ((bid >> 3) & 3);
    const int a    = bid >> 5;                       // 0..15
    const int j    = (a < 8) ? (15 - a) : (a - 8);   // 128-row q-block, heaviest first
    const int b    = head & (NBATCH - 1);
    const size_t hoff = (size_t)head * S_LEN * DHEAD;

    const int q0w = (j << 7) + (wave << 5);          // this wave's first q row
    const int dq  = q0w + lq;                        // this lane's q row
    const int nt  = (q0w >> 5) + 1;                  // KV tiles (32 keys) for this wave

    char* wbase = SMEM + (wave << 14);
    const int swzq = (lq ^ (lq >> 2)) & 3;           // P-buffer 16B-slot swizzle (R5-verified)

    const ushort_t* kbase = Kb + hoff;
    const ushort_t* vbase = Vt + (size_t)head * DHEAD * S_LEN;

    // ---- mask words: one per lane (64 words cover all 2048 keys) ----
    unsigned mwords = mbits[(b << 6) + lane];

    // ---- Q B-frags (col=lane&31=q, k=hi*8+i), scale 0.125*log2e folded in ----
    bh8 qB[4];
    {
        const float* qp = Q + hoff + (size_t)(q0w + lq) * DHEAD;
        const float qs = 0.125f * LOG2E;
        #pragma unroll
        for (int ks = 0; ks < 4; ++ks){
            f4 f0 = *(const f4*)(qp + ks * 16 + hi * 8);
            f4 f1 = *(const f4*)(qp + ks * 16 + hi * 8 + 4);
            bh8 aa;
            #pragma unroll
            for (int i = 0; i < 4; ++i){
                aa[i]   = (short)f2b(f0[i] * qs);
                aa[i+4] = (short)f2b(f1[i] * qs);
            }
            qB[ks] = aa;
        }
    }

    // wave-private stage of one 32-key tile: K 4KB (+0/+4K) and V 4KB (+8K/+12K).
    // V LDS rows are 128B = [d=r (64B) | d=r+32 (64B)], keys kv0..kv0+31;
    // both use the (row&7)<<4 XOR swizzle via pre-swizzled global source.
    auto stage = [&](int buf, int kv0){
        char* kdst = wbase + (buf << 12);
        char* vdst = wbase + 8192 + (buf << 12);
        #pragma unroll
        for (int i = 0; i < 4; ++i){
            const int row = (i << 3) + (lane >> 3);            // 0..31
            const int osw = ((lane & 7) << 4) ^ ((row & 7) << 4);
            const char* ks = (const char*)kbase + (size_t)(kv0 + row) * 128 + osw;
            __builtin_amdgcn_global_load_lds(
                (const __attribute__((address_space(1))) void*)ks,
                (__attribute__((address_space(3))) void*)(kdst + (i << 10)), 16, 0, 0);
            const int d   = row + ((osw >> 6) << 5);
            const char* vs = (const char*)vbase + (size_t)d * (S_LEN * 2)
                             + (size_t)kv0 * 2 + (osw & 63);
            __builtin_amdgcn_global_load_lds(
                (const __attribute__((address_space(1))) void*)vs,
                (__attribute__((address_space(3))) void*)(vdst + (i << 10)), 16, 0, 0);
        }
    };

    f16x acc0 = {};   // O^T rows d=0..31:  col=q=lq, row d=(reg&3)+8*(reg>>2)+4*hi
    f16x acc1 = {};   // O^T rows d=32..63
    f16x accL = {};   // row-sum accumulator: every reg = l[q=lq]; only reg 0 maintained
    float m = -INFINITY;
    const bh8 ones = {(short)0x3F80, (short)0x3F80, (short)0x3F80, (short)0x3F80,
                      (short)0x3F80, (short)0x3F80, (short)0x3F80, (short)0x3F80};

    // drain Q/mask loads so in-loop vmcnt counting sees only stage loads
    asm volatile("s_waitcnt vmcnt(0)" ::: "memory");
    stage(0, 0);
    if (nt > 1) stage(1, 32);

    for (int kt = 0; kt < nt; ++kt){
        const int cur = kt & 1;
        const int kv0 = kt << 5;
        if (kt + 1 < nt) asm volatile("s_waitcnt vmcnt(8)" ::: "memory");
        else             asm volatile("s_waitcnt vmcnt(0)" ::: "memory");
        __builtin_amdgcn_sched_barrier(0);

        char* kbuf = wbase + (cur << 12);
        char* vbuf = wbase + 8192 + (cur << 12);

        // ---- K A-frags (rows = 32 keys, 128B, swizzled) ----
        bh8 kf[4];
        #pragma unroll
        for (int ks = 0; ks < 4; ++ks){
            const int cb = ((ks << 5) + (hi << 4)) ^ ((lq & 7) << 4);
            kf[ks] = *(const bh8*)(kbuf + (lq << 7) + cb);
        }

        // ---- S^T = K Q^T ----
        f16x s = {};
        __builtin_amdgcn_s_setprio(1);
        #pragma unroll
        for (int ks = 0; ks < 4; ++ks)
            s = __builtin_amdgcn_mfma_f32_32x32x16_bf16(kf[ks], qB[ks], s, 0, 0, 0);
        __builtin_amdgcn_s_setprio(0);

        // ---- V A-frags: row lq = [d=lq | d=lq+32], swizzled ----
        bh8 vf[4];
        #pragma unroll
        for (int aa = 0; aa < 2; ++aa)
            #pragma unroll
            for (int kk = 0; kk < 2; ++kk){
                const int cb = ((aa << 6) + (kk << 5) + (hi << 4)) ^ ((lq & 7) << 4);
                vf[aa * 2 + kk] = *(const bh8*)(vbuf + (lq << 7) + cb);
            }

        // ---- key-padding (one readlane word) ; causal on last tile ----
        const unsigned ml = ((unsigned)__builtin_amdgcn_readlane(
                                 __builtin_bit_cast(int, mwords), kt)) >> (hi << 2);
        #pragma unroll
        for (int g = 0; g < 4; ++g)
            #pragma unroll
            for (int i = 0; i < 4; ++i)
                s[g*4+i] = ((ml >> (g*8+i)) & 1u) ? CMASK : s[g*4+i];
        if (kt == nt - 1){
            #pragma unroll
            for (int g = 0; g < 4; ++g)
                #pragma unroll
                for (int i = 0; i < 4; ++i)
                    s[g*4+i] = (kv0 + (g<<3) + (hi<<2) + i > dq) ? CMASK : s[g*4+i];
        }

        // ---- row max: local tree + cross-half shfl ----
        float t8[8];
        #pragma unroll
        for (int i = 0; i < 8; ++i) t8[i] = fmaxf(s[i], s[i+8]);
        #pragma unroll
        for (int i = 0; i < 4; ++i) t8[i] = fmaxf(t8[i], t8[i+4]);
        float pml = fmaxf(fmaxf(t8[0], t8[1]), fmaxf(t8[2], t8[3]));
        float pm  = fmaxf(pml, __shfl_xor(pml, 32, 64));

        // ---- deferred rescale (log2 units) ----
        if (!__all(pm <= m + 11.0f)){
            float mn = fmaxf(m, pm);
            float al = __builtin_amdgcn_exp2f(m - mn);
            m = mn;
            accL[0] *= al;
            #pragma unroll
            for (int i = 0; i < 16; ++i){ acc0[i] *= al; acc1[i] *= al; }
        }

        // ---- P = exp2(S - m) ----
        #pragma unroll
        for (int i = 0; i < 16; ++i) s[i] = __builtin_amdgcn_exp2f(s[i] - m);

        // ---- P -> LDS (aliases low 2KB of V[cur], already consumed) -> B-frags ----
        asm volatile("s_waitcnt lgkmcnt(0)" ::: "memory");   // vf reads done (WAR)
        __builtin_amdgcn_sched_barrier(0);
        char* pw = vbuf + (lq << 6);
        #pragma unroll
        for (int g = 0; g < 4; ++g){
            i2 w;
            w[0] = pack2(s[g*4+0], s[g*4+1]);
            w[1] = pack2(s[g*4+2], s[g*4+3]);
            *(i2*)(pw + ((g ^ swzq) << 4) + (hi << 3)) = w;
        }
        asm volatile("s_waitcnt lgkmcnt(0)" ::: "memory");
        __builtin_amdgcn_sched_barrier(0);
        bh8 pa[2];
        pa[0] = *(const bh8*)(pw + ((hi ^ swzq) << 4));          // keys hi*8+0..7
        pa[1] = *(const bh8*)(pw + (((2 | hi) ^ swzq) << 4));    // keys 16+hi*8+0..7

        // ---- O^T += V^T P^T ; l via MFMA ones-trick ----
        __builtin_amdgcn_s_setprio(1);
        #pragma unroll
        for (int kk = 0; kk < 2; ++kk){
            acc0 = __builtin_amdgcn_mfma_f32_32x32x16_bf16(vf[kk],     pa[kk], acc0, 0, 0, 0);
            acc1 = __builtin_amdgcn_mfma_f32_32x32x16_bf16(vf[2 + kk], pa[kk], acc1, 0, 0, 0);
            accL = __builtin_amdgcn_mfma_f32_32x32x16_bf16(ones,       pa[kk], accL, 0, 0, 0);
        }
        __builtin_amdgcn_s_setprio(0);

        // ---- prefetch tile kt+2 into buf cur (P + reads already consumed) ----
        if (kt + 2 < nt) stage(cur, (kt + 2) << 5);
    }

    // ---- epilogue: O[q][d] = acc/l ; reg g*4+i -> d = 8g+4hi+i ----
    const float inv = 1.0f / accL[0];
    float* op = Out + hoff + (size_t)(q0w + lq) * DHEAD;
    #pragma unroll
    for (int g = 0; g < 4; ++g){
        f4 o0, o1;
        #pragma unroll
        for (int i = 0; i < 4; ++i){
            o0[i] = acc0[g * 4 + i] * inv;
            o1[i] = acc1[g * 4 + i] * inv;
        }
        *(f4*)(op + g * 8 + hi * 4)      = o0;
        *(f4*)(op + 32 + g * 8 + hi * 4) = o1;
    }
}

// Rows q < q* (q* = first unmasked key of the batch): reference softmax is uniform over
// ALL 2048 keys -> output = column mean of V. Reduce prep's 32 partial sums per head.
__global__ __launch_bounds__(256)
void attn_fixup(const float* __restrict__ colpart, const int* __restrict__ M,
                float* __restrict__ Out)
{
    __shared__ float red[4][64];
    __shared__ int qstar;
    const int head = blockIdx.x;
    const int b = head & (NBATCH - 1);
    const int tid = threadIdx.x;
    const int col = tid & 63;
    const int grp = tid >> 6;
    {
        float s = 0.f;
        const float* cp = colpart + ((size_t)head * 32 + grp * 8) * 64 + col;
        #pragma unroll
        for (int j = 0; j < 8; ++j) s += cp[j * 64];
        red[grp][col] = s;
    }
    if (tid == 0){
        int q = 0;
        const int* mp = M + (size_t)b * S_LEN;
        while (q < S_LEN && mp[q]) ++q;
        qstar = q;
    }
    __syncthreads();
    const int qs = qstar;
    if (qs == 0) return;
    const float mean = (red[0][col] + red[1][col] + red[2][col] + red[3][col])
                       * (1.0f / S_LEN);
    for (int q = grp; q < qs; q += 4)
        Out[((size_t)head * S_LEN + q) * DHEAD + col] = mean;
}

extern "C" void kernel_launch(void* const* d_in, const int* in_sizes, int n_in,
                              void* d_out, int out_size, void* d_ws, size_t ws_size,
                              hipStream_t stream)
{
    const float* Q = (const float*)d_in[0];
    const float* K = (const float*)d_in[1];
    const float* V = (const float*)d_in[2];
    const int*   M = (const int*)d_in[3];
    float* Out = (float*)d_out;

    ushort_t* Kb = (ushort_t*)d_ws;                                  // 8.39 MB
    ushort_t* Vt = Kb + (size_t)NHEADS * S_LEN * DHEAD;              // 8.39 MB
    float* colpart = (float*)(Vt + (size_t)NHEADS * S_LEN * DHEAD);  // 256 KB
    unsigned* mbits = (unsigned*)(colpart + 1024 * 64);              // 1 KB

    prep      <<<dim3(3073),   dim3(256), 0, stream>>>(K, V, M, Kb, Vt, colpart, mbits);
    attn_main <<<dim3(512),    dim3(256), 0, stream>>>(Q, Kb, Vt, mbits, Out);
    attn_fixup<<<dim3(NHEADS), dim3(256), 0, stream>>>(colpart, M, Out);
}